// Round 9
// baseline (575.166 us; speedup 1.0000x reference)
//
#include <hip/hip_runtime.h>
#include <math.h>

#define N_NODES 50000
#define N_EDGES 800000
#define N_GRAPHS 512
#define D 64
#define DE 32
#define NTILE (N_EDGES / 16)   // 50000 16-edge tiles
#define NB_SCAN 196            // ceil(50000/256)
#define LSTR 68                // LDS row stride (floats), bank-spread

// ---------------------------------------------------------------------------
// R8 lesson: fused LDS aggregation works (551us). Remaining: NT re-reads the
// A-tile 16x (200MB H traffic), and the edge kernel gathers ea via perm
// (102MB fp32, random 128B granules, done per layer).
// R9: (a) pack_ea pre-pass writes bf16 ea rows in sorted order ONCE ->
// edge A-frag is a coalesced 16B load, no perm/cvt in edge kernel.
// (b) NT: wave = (ntile, 8-cb half); A-frags loaded once, reused across 8
// column blocks. (c) rest = R8.
//
// MFMA 16x16x32 bf16 fragment maps (m89/m120-verified):
//   A[m][k]: m = lane&15, k = (lane>>4)*8 + i
//   B[k][n]: n = lane&15, k = (lane>>4)*8 + i
//   C/D    : col n = lane&15, row m = (lane>>4)*4 + reg
// ---------------------------------------------------------------------------

typedef __attribute__((ext_vector_type(8))) short short8;
typedef __attribute__((ext_vector_type(4))) float floatx4;
union Frag { short8 s; unsigned u[4]; };

__device__ inline unsigned pk_bf16(float lo, float hi) {
    unsigned a = __float_as_uint(lo);
    unsigned b = __float_as_uint(hi);
    a = (a + 0x7FFFu + ((a >> 16) & 1u)) >> 16;
    b = (b + 0x7FFFu + ((b >> 16) & 1u)) >> 16;
    return a | (b << 16);
}
__device__ inline unsigned short bf16_1(float v) {
    unsigned a = __float_as_uint(v);
    return (unsigned short)((a + 0x7FFFu + ((a >> 16) & 1u)) >> 16);
}
__device__ inline float upk(unsigned u16) { return __uint_as_float(u16 << 16); }

// ---------------- CSR build (once per call) --------------------------------
__global__ __launch_bounds__(256) void hist_kernel(
    const int* __restrict__ ei, int* __restrict__ deg)
{
    int e = blockIdx.x * 256 + threadIdx.x;
    atomicAdd(&deg[ei[N_EDGES + e]], 1);
}

__global__ __launch_bounds__(256) void scan1(
    const int* __restrict__ deg, int* __restrict__ off, int* __restrict__ tsum)
{
    __shared__ int s[256];
    int i = blockIdx.x * 256 + threadIdx.x;
    s[threadIdx.x] = (i < N_NODES) ? deg[i] : 0;
    __syncthreads();
    if (threadIdx.x == 0) {
        int run = 0;
        for (int k = 0; k < 256; ++k) { int t = s[k]; s[k] = run; run += t; }
        tsum[blockIdx.x] = run;
    }
    __syncthreads();
    if (i < N_NODES) off[i] = s[threadIdx.x];
}

__global__ __launch_bounds__(256) void scan2(int* __restrict__ tsum)
{
    __shared__ int s[256];
    int i = threadIdx.x;
    s[i] = (i < NB_SCAN) ? tsum[i] : 0;
    __syncthreads();
    if (i == 0) {
        int run = 0;
        for (int k = 0; k < NB_SCAN; ++k) { int t = s[k]; s[k] = run; run += t; }
    }
    __syncthreads();
    if (i < NB_SCAN) tsum[i] = s[i];
}

__global__ __launch_bounds__(256) void scan3(
    int* __restrict__ off, const int* __restrict__ tsum)
{
    int i = blockIdx.x * 256 + threadIdx.x;
    if (i < N_NODES) off[i] += tsum[blockIdx.x];
    if (i == N_NODES) off[i] = N_EDGES;
}

__global__ __launch_bounds__(256) void scatter_kernel(
    const int* __restrict__ ei, const int* __restrict__ off,
    int* __restrict__ cnt, int* __restrict__ perm,
    int* __restrict__ src_sorted, int* __restrict__ dst_sorted)
{
    int e = blockIdx.x * 256 + threadIdx.x;
    int s = ei[e];
    int d = ei[N_EDGES + e];
    int r = atomicAdd(&cnt[d], 1);
    int pos = off[d] + r;
    perm[pos] = e;
    src_sorted[pos] = s;
    dst_sorted[pos] = d;
}

// ---- pack_ea: eaS[pos][32] = bf16(ea[perm[pos]][:]), coalesced write ------
// thread t: pos = t>>5, c = t&31
__global__ __launch_bounds__(256) void pack_ea(
    const float* __restrict__ ea, const int* __restrict__ perm,
    unsigned short* __restrict__ eaS)
{
    const int t = blockIdx.x * 256 + threadIdx.x;
    const int pos = t >> 5;
    const int c   = t & 31;
    const int e = perm[pos];
    eaS[(size_t)pos * 32 + c] = bf16_1(ea[(size_t)e * 32 + c]);
}

// ---- node transform: Tdst/Tsrc = bf16[H @ W parts], (f,s)-pair layout -----
// wave = (ntile, half): A-frags loaded once, reused for 8 column blocks.
__global__ __launch_bounds__(256) void node_transform_mfma(
    const float* __restrict__ H,
    const float* __restrict__ Wf,
    const float* __restrict__ Ws,
    const float* __restrict__ bf,
    const float* __restrict__ bs,
    unsigned short* __restrict__ Tdst,    // [N_NODES][128]
    unsigned short* __restrict__ Tsrc)    // [N_NODES][128]
{
    const int lane = threadIdx.x & 63;
    const int wid  = threadIdx.x >> 6;
    const int n16  = lane & 15;
    const int quad = lane >> 4;
    const int kc   = quad * 8;

    const int gid = blockIdx.x * 4 + wid;           // global wave id
    const int NW  = (N_NODES / 16) * 2;             // 6250 waves of work
    if (gid >= NW) return;
    const int ntile = gid >> 1;
    const int cb0   = (gid & 1) * 8;

    // A fragments once per wave
    const float* hrow = H + (size_t)(ntile * 16 + n16) * D;
    float4 q0 = *(const float4*)(hrow + kc);
    float4 q1 = *(const float4*)(hrow + kc + 4);
    float4 q2 = *(const float4*)(hrow + 32 + kc);
    float4 q3 = *(const float4*)(hrow + 32 + kc + 4);
    Frag a0, a1;
    a0.u[0] = pk_bf16(q0.x, q0.y); a0.u[1] = pk_bf16(q0.z, q0.w);
    a0.u[2] = pk_bf16(q1.x, q1.y); a0.u[3] = pk_bf16(q1.z, q1.w);
    a1.u[0] = pk_bf16(q2.x, q2.y); a1.u[1] = pk_bf16(q2.z, q2.w);
    a1.u[2] = pk_bf16(q3.x, q3.y); a1.u[3] = pk_bf16(q3.z, q3.w);

#pragma unroll
    for (int cbi = 0; cbi < 8; ++cbi) {
        const int cb  = cb0 + cbi;
        const int jj  = cb * 16 + n16;       // 0..255
        const int part  = jj >> 7;           // 0: dst-part, 1: src-part
        const int col   = jj & 127;
        const int sflag = jj & 1;
        const int j     = (jj >> 1) & 63;
        const float* Wsel = sflag ? Ws : Wf;
        const int rbase = part * 64;
        unsigned short* Tout = part ? Tsrc : Tdst;

        Frag b0, b1;
        {
            float t0[8], t1[8];
#pragma unroll
            for (int i = 0; i < 8; ++i) {
                t0[i] = Wsel[(rbase + kc + i) * 64 + j];
                t1[i] = Wsel[(rbase + 32 + kc + i) * 64 + j];
            }
#pragma unroll
            for (int p = 0; p < 4; ++p) {
                b0.u[p] = pk_bf16(t0[2 * p], t0[2 * p + 1]);
                b1.u[p] = pk_bf16(t1[2 * p], t1[2 * p + 1]);
            }
        }
        float bias = 0.0f;
        if (part == 0) bias = sflag ? bs[j] : bf[j];

        floatx4 acc = {bias, bias, bias, bias};
        acc = __builtin_amdgcn_mfma_f32_16x16x32_bf16(a0.s, b0.s, acc, 0, 0, 0);
        acc = __builtin_amdgcn_mfma_f32_16x16x32_bf16(a1.s, b1.s, acc, 0, 0, 0);

#pragma unroll
        for (int r = 0; r < 4; ++r) {
            const int node = ntile * 16 + quad * 4 + r;
            Tout[(size_t)node * 128 + col] = bf16_1(acc[r]);
        }
    }
}

// ---- edge kernel with fused segmented aggregation -------------------------
__global__ __launch_bounds__(256) void edge_message_mfma(
    const unsigned short* __restrict__ Tdst,  // [N_NODES][128] bf16
    const unsigned short* __restrict__ Tsrc,  // [N_NODES][128] bf16
    const unsigned short* __restrict__ eaS,   // [N_EDGES][32] bf16, sorted
    const int* __restrict__ src_sorted,       // [N_EDGES]
    const int* __restrict__ dst_sorted,       // [N_EDGES] non-decreasing
    const float* __restrict__ Wf,             // rows 128..159 used
    const float* __restrict__ Ws,
    float* __restrict__ hout)                 // [N_NODES][64], pre-init = hin
{
    __shared__ float lds[4][16 * LSTR];
    const int lane = threadIdx.x & 63;
    const int wid  = threadIdx.x >> 6;
    const int n16  = lane & 15;
    const int quad = lane >> 4;
    const int c0   = quad * 8;
    float* L = lds[wid];

    Frag bfr[4], bsr[4];
#pragma unroll
    for (int jb = 0; jb < 4; ++jb) {
        const int j = jb * 16 + n16;
        float tf[8], tsv[8];
#pragma unroll
        for (int i = 0; i < 8; ++i) {
            tf[i]  = Wf[(128 + c0 + i) * 64 + j];
            tsv[i] = Ws[(128 + c0 + i) * 64 + j];
        }
#pragma unroll
        for (int p = 0; p < 4; ++p) {
            bfr[jb].u[p] = pk_bf16(tf[2 * p], tf[2 * p + 1]);
            bsr[jb].u[p] = pk_bf16(tsv[2 * p], tsv[2 * p + 1]);
        }
    }

    const floatx4 zero = {0.0f, 0.0f, 0.0f, 0.0f};
    const int nwaves = gridDim.x * 4;
    for (int t = blockIdx.x * 4 + wid; t < NTILE; t += nwaves) {
        const int p0 = t * 16;

        // per-tile metadata: lanes 0..15 meaningful (others mirror)
        const int sv16 = src_sorted[p0 + n16];
        const int dv16 = dst_sorted[p0 + n16];

        // A fragment: one coalesced 16B bf16 load (sorted layout)
        Frag af;
        af.s = *(const short8*)(eaS + (size_t)(p0 + n16) * 32 + c0);

        floatx4 accf[4], accs[4];
#pragma unroll
        for (int jb = 0; jb < 4; ++jb) {
            accf[jb] = __builtin_amdgcn_mfma_f32_16x16x32_bf16(af.s, bfr[jb].s, zero, 0, 0, 0);
            accs[jb] = __builtin_amdgcn_mfma_f32_16x16x32_bf16(af.s, bsr[jb].s, zero, 0, 0, 0);
        }

        // activation + write message rows into wave-private LDS
#pragma unroll
        for (int r = 0; r < 4; ++r) {
            const int m = quad * 4 + r;               // row (sorted pos p0+m)
            const int sv = __shfl(sv16, m);           // src of row m
            const int dv = __shfl(dv16, m);           // dst of row m
            const unsigned short* td = Tdst + (size_t)dv * 128;
            const unsigned short* ts = Tsrc + (size_t)sv * 128;
#pragma unroll
            for (int jb = 0; jb < 4; ++jb) {
                const int j = jb * 16 + n16;
                unsigned d2 = *(const unsigned*)(td + 2 * j);
                unsigned s2 = *(const unsigned*)(ts + 2 * j);
                float vf = accf[jb][r] + upk(d2 & 0xFFFFu) + upk(s2 & 0xFFFFu);
                float vs = accs[jb][r] + upk(d2 >> 16) + upk(s2 >> 16);
                float sig = __builtin_amdgcn_rcpf(1.0f + __expf(-vf));
                float spl = fmaxf(vs, 0.0f) + __logf(1.0f + __expf(-fabsf(vs)));
                L[m * LSTR + j] = sig * spl;
            }
        }

        // segmented scan over the 16 rows (dst runs), lane = channel
        {
            int cur = __builtin_amdgcn_readlane(dv16, 0);
            float acc = L[0 * LSTR + lane];
#pragma unroll
            for (int r = 1; r < 16; ++r) {
                int d = __builtin_amdgcn_readlane(dv16, r);
                float v = L[r * LSTR + lane];
                if (d != cur) {
                    atomicAdd(&hout[(size_t)cur * D + lane], acc);
                    cur = d; acc = v;
                } else {
                    acc += v;
                }
            }
            atomicAdd(&hout[(size_t)cur * D + lane], acc);
        }
    }
}

// segment_sum(h, batch) into pooled[N_GRAPHS][64]
__global__ __launch_bounds__(256) void pool_kernel(
    const float* __restrict__ h,
    const int* __restrict__ batch,
    float* __restrict__ pooled)
{
    const int lane = threadIdx.x & 63;
    const int wid  = threadIdx.x >> 6;
    const int n = blockIdx.x * 4 + wid;
    if (n >= N_NODES) return;
    atomicAdd(&pooled[(size_t)batch[n] * D + lane], h[(size_t)n * D + lane]);
}

__global__ __launch_bounds__(256) void out_kernel(
    const float* __restrict__ pooled,
    const float* __restrict__ Wout,
    const float* __restrict__ bout,
    float* __restrict__ out)
{
    const int g = blockIdx.x * blockDim.x + threadIdx.x;
    if (g >= N_GRAPHS) return;
    float acc = bout[0];
#pragma unroll
    for (int j = 0; j < D; ++j) acc = fmaf(pooled[(size_t)g * D + j], Wout[j], acc);
    out[g] = acc;
}

extern "C" void kernel_launch(void* const* d_in, const int* in_sizes, int n_in,
                              void* d_out, int out_size, void* d_ws, size_t ws_size,
                              hipStream_t stream) {
    const float* x     = (const float*)d_in[0];
    const int*   ei    = (const int*)  d_in[1];
    const float* ea    = (const float*)d_in[2];
    const int*   batch = (const int*)  d_in[3];
    const float* Wf1   = (const float*)d_in[4];
    const float* bf1   = (const float*)d_in[5];
    const float* Ws1   = (const float*)d_in[6];
    const float* bs1   = (const float*)d_in[7];
    const float* Wf2   = (const float*)d_in[8];
    const float* bf2   = (const float*)d_in[9];
    const float* Ws2   = (const float*)d_in[10];
    const float* bs2   = (const float*)d_in[11];
    const float* Wout  = (const float*)d_in[12];
    const float* bout  = (const float*)d_in[13];
    float* out = (float*)d_out;

    // workspace carve (~117 MB)
    char* base = (char*)d_ws;
    size_t o = 0;
    unsigned short* Tdst = (unsigned short*)(base + o); o += (size_t)N_NODES * 128 * 2;
    unsigned short* Tsrc = (unsigned short*)(base + o); o += (size_t)N_NODES * 128 * 2;
    unsigned short* eaS  = (unsigned short*)(base + o); o += (size_t)N_EDGES * 32 * 2;
    float* h1     = (float*)(base + o); o += (size_t)N_NODES * D * 4;
    float* h2     = (float*)(base + o); o += (size_t)N_NODES * D * 4;
    float* pooled = (float*)(base + o); o += (size_t)N_GRAPHS * D * 4;
    int* deg  = (int*)(base + o); o += (size_t)N_NODES * 4;
    int* off  = (int*)(base + o); o += (size_t)(N_NODES + 1) * 4;
    int* tsum = (int*)(base + o); o += 256 * 4;
    int* perm = (int*)(base + o); o += (size_t)N_EDGES * 4;
    int* src_sorted = (int*)(base + o); o += (size_t)N_EDGES * 4;
    int* dst_sorted = (int*)(base + o); o += (size_t)N_EDGES * 4;

    // ---- CSR build + ea pre-pack ----
    hipMemsetAsync(deg, 0, (size_t)N_NODES * 4, stream);
    hist_kernel<<<N_EDGES / 256, 256, 0, stream>>>(ei, deg);
    scan1<<<NB_SCAN, 256, 0, stream>>>(deg, off, tsum);
    scan2<<<1, 256, 0, stream>>>(tsum);
    scan3<<<NB_SCAN, 256, 0, stream>>>(off, tsum);
    hipMemsetAsync(deg, 0, (size_t)N_NODES * 4, stream);
    scatter_kernel<<<N_EDGES / 256, 256, 0, stream>>>(ei, off, deg, perm,
                                                      src_sorted, dst_sorted);
    pack_ea<<<N_EDGES * 32 / 256, 256, 0, stream>>>(ea, perm, eaS);

    // ---- layer 1 ----
    node_transform_mfma<<<1563, 256, 0, stream>>>(x, Wf1, Ws1, bf1, bs1, Tdst, Tsrc);
    hipMemcpyAsync(h1, x, (size_t)N_NODES * D * 4, hipMemcpyDeviceToDevice, stream);
    edge_message_mfma<<<3125, 256, 0, stream>>>(Tdst, Tsrc, eaS,
                                                src_sorted, dst_sorted, Wf1, Ws1, h1);

    // ---- layer 2 ----
    node_transform_mfma<<<1563, 256, 0, stream>>>(h1, Wf2, Ws2, bf2, bs2, Tdst, Tsrc);
    hipMemcpyAsync(h2, h1, (size_t)N_NODES * D * 4, hipMemcpyDeviceToDevice, stream);
    edge_message_mfma<<<3125, 256, 0, stream>>>(Tdst, Tsrc, eaS,
                                                src_sorted, dst_sorted, Wf2, Ws2, h2);

    // ---- pool + out ----
    hipMemsetAsync(pooled, 0, (size_t)N_GRAPHS * D * 4, stream);
    pool_kernel<<<12500, 256, 0, stream>>>(h2, batch, pooled);
    out_kernel<<<2, 256, 0, stream>>>(pooled, Wout, bout, out);
}

// Round 10
// 506.107 us; speedup vs baseline: 1.1365x; 1.1365x over previous
//
#include <hip/hip_runtime.h>
#include <math.h>

#define N_NODES 50000
#define N_EDGES 800000
#define N_GRAPHS 512
#define D 64
#define DE 32
#define NTILE (N_EDGES / 16)   // 50000 16-edge tiles
#define NB_SCAN 196            // ceil(50000/256)
#define LSTR 68                // edge LDS row stride (floats)
#define NSTR 136               // NT LDS row stride (ushorts), 272B = 16B-aligned

// ---------------------------------------------------------------------------
// R9 lesson: gather-direction pack_ea (random 128B reads) ran at 1.17 TB/s =
// 94us. R10: invert — scatter_pack streams ea coalesced (thread = original
// edge) and scatter-writes bf16 rows to eaS[pos] (random 64B WRITES are
// fire-and-forget). perm eliminated; (src,dst) packed into one int2 array.
// NT: stores were 64 scattered 2B per wave -> LDS transpose + 4 uint4 stores.
//
// MFMA 16x16x32 bf16 fragment maps (m89/m120-verified):
//   A[m][k]: m = lane&15, k = (lane>>4)*8 + i
//   B[k][n]: n = lane&15, k = (lane>>4)*8 + i
//   C/D    : col n = lane&15, row m = (lane>>4)*4 + reg
// ---------------------------------------------------------------------------

typedef __attribute__((ext_vector_type(8))) short short8;
typedef __attribute__((ext_vector_type(4))) float floatx4;
union Frag { short8 s; unsigned u[4]; };

__device__ inline unsigned pk_bf16(float lo, float hi) {
    unsigned a = __float_as_uint(lo);
    unsigned b = __float_as_uint(hi);
    a = (a + 0x7FFFu + ((a >> 16) & 1u)) >> 16;
    b = (b + 0x7FFFu + ((b >> 16) & 1u)) >> 16;
    return a | (b << 16);
}
__device__ inline unsigned short bf16_1(float v) {
    unsigned a = __float_as_uint(v);
    return (unsigned short)((a + 0x7FFFu + ((a >> 16) & 1u)) >> 16);
}
__device__ inline float upk(unsigned u16) { return __uint_as_float(u16 << 16); }

// ---------------- CSR build (once per call) --------------------------------
__global__ __launch_bounds__(256) void hist_kernel(
    const int* __restrict__ ei, int* __restrict__ deg)
{
    int e = blockIdx.x * 256 + threadIdx.x;
    atomicAdd(&deg[ei[N_EDGES + e]], 1);
}

__global__ __launch_bounds__(256) void scan1(
    const int* __restrict__ deg, int* __restrict__ off, int* __restrict__ tsum)
{
    __shared__ int s[256];
    int i = blockIdx.x * 256 + threadIdx.x;
    s[threadIdx.x] = (i < N_NODES) ? deg[i] : 0;
    __syncthreads();
    if (threadIdx.x == 0) {
        int run = 0;
        for (int k = 0; k < 256; ++k) { int t = s[k]; s[k] = run; run += t; }
        tsum[blockIdx.x] = run;
    }
    __syncthreads();
    if (i < N_NODES) off[i] = s[threadIdx.x];
}

__global__ __launch_bounds__(256) void scan2(int* __restrict__ tsum)
{
    __shared__ int s[256];
    int i = threadIdx.x;
    s[i] = (i < NB_SCAN) ? tsum[i] : 0;
    __syncthreads();
    if (i == 0) {
        int run = 0;
        for (int k = 0; k < NB_SCAN; ++k) { int t = s[k]; s[k] = run; run += t; }
    }
    __syncthreads();
    if (i < NB_SCAN) tsum[i] = s[i];
}

__global__ __launch_bounds__(256) void scan3(
    int* __restrict__ off, const int* __restrict__ tsum)
{
    int i = blockIdx.x * 256 + threadIdx.x;
    if (i < N_NODES) off[i] += tsum[blockIdx.x];
    if (i == N_NODES) off[i] = N_EDGES;
}

// scatter + ea pack in one pass: read side coalesced, write side random 64B
__global__ __launch_bounds__(256) void scatter_pack(
    const int* __restrict__ ei, const int* __restrict__ off,
    int* __restrict__ cnt, const float* __restrict__ ea,
    unsigned short* __restrict__ eaS,      // [N_EDGES][32] bf16, sorted order
    int2* __restrict__ sd_sorted)          // [N_EDGES] (src,dst), sorted
{
    int e = blockIdx.x * 256 + threadIdx.x;
    int s = ei[e];
    int d = ei[N_EDGES + e];
    int r = atomicAdd(&cnt[d], 1);
    int pos = off[d] + r;
    sd_sorted[pos] = make_int2(s, d);

    const float4* src4 = (const float4*)(ea + (size_t)e * 32);
    uint4* dst16 = (uint4*)(eaS + (size_t)pos * 32);
#pragma unroll
    for (int q = 0; q < 2; ++q) {
        float4 v0 = src4[4 * q + 0];
        float4 v1 = src4[4 * q + 1];
        float4 v2 = src4[4 * q + 2];
        float4 v3 = src4[4 * q + 3];
        uint4 o0;
        o0.x = pk_bf16(v0.x, v0.y); o0.y = pk_bf16(v0.z, v0.w);
        o0.z = pk_bf16(v1.x, v1.y); o0.w = pk_bf16(v1.z, v1.w);
        uint4 o1;
        o1.x = pk_bf16(v2.x, v2.y); o1.y = pk_bf16(v2.z, v2.w);
        o1.z = pk_bf16(v3.x, v3.y); o1.w = pk_bf16(v3.z, v3.w);
        dst16[2 * q + 0] = o0;
        dst16[2 * q + 1] = o1;
    }
}

// ---- node transform: Tdst/Tsrc = bf16[H @ W parts], (f,s)-pair layout -----
// wave = (ntile, part). A-frags loaded once; 8 column blocks accumulated to a
// wave-private LDS tile; 4 coalesced uint4 stores per wave iter (R10).
__global__ __launch_bounds__(256) void node_transform_mfma(
    const float* __restrict__ H,
    const float* __restrict__ Wf,
    const float* __restrict__ Ws,
    const float* __restrict__ bf,
    const float* __restrict__ bs,
    unsigned short* __restrict__ Tdst,    // [N_NODES][128]
    unsigned short* __restrict__ Tsrc)    // [N_NODES][128]
{
    __shared__ unsigned short lt[4][16 * NSTR];
    const int lane = threadIdx.x & 63;
    const int wid  = threadIdx.x >> 6;
    const int n16  = lane & 15;
    const int quad = lane >> 4;
    const int kc   = quad * 8;
    unsigned short* L = lt[wid];

    const int gid = blockIdx.x * 4 + wid;           // global wave id
    const int NW  = (N_NODES / 16) * 2;             // 6250 waves of work
    if (gid >= NW) return;
    const int ntile = gid >> 1;
    const int part  = gid & 1;                      // 0: dst-part, 1: src-part
    unsigned short* Tout = part ? Tsrc : Tdst;
    const int rbase = part * 64;

    // A fragments once per wave
    const float* hrow = H + (size_t)(ntile * 16 + n16) * D;
    float4 q0 = *(const float4*)(hrow + kc);
    float4 q1 = *(const float4*)(hrow + kc + 4);
    float4 q2 = *(const float4*)(hrow + 32 + kc);
    float4 q3 = *(const float4*)(hrow + 32 + kc + 4);
    Frag a0, a1;
    a0.u[0] = pk_bf16(q0.x, q0.y); a0.u[1] = pk_bf16(q0.z, q0.w);
    a0.u[2] = pk_bf16(q1.x, q1.y); a0.u[3] = pk_bf16(q1.z, q1.w);
    a1.u[0] = pk_bf16(q2.x, q2.y); a1.u[1] = pk_bf16(q2.z, q2.w);
    a1.u[2] = pk_bf16(q3.x, q3.y); a1.u[3] = pk_bf16(q3.z, q3.w);

#pragma unroll
    for (int cbi = 0; cbi < 8; ++cbi) {
        const int col   = cbi * 16 + n16;    // 0..127 within this part
        const int sflag = col & 1;           // 0: f, 1: s
        const int j     = col >> 1;          // output channel 0..63
        const float* Wsel = sflag ? Ws : Wf;

        Frag b0, b1;
        {
            float t0[8], t1[8];
#pragma unroll
            for (int i = 0; i < 8; ++i) {
                t0[i] = Wsel[(rbase + kc + i) * 64 + j];
                t1[i] = Wsel[(rbase + 32 + kc + i) * 64 + j];
            }
#pragma unroll
            for (int p = 0; p < 4; ++p) {
                b0.u[p] = pk_bf16(t0[2 * p], t0[2 * p + 1]);
                b1.u[p] = pk_bf16(t1[2 * p], t1[2 * p + 1]);
            }
        }
        float bias = 0.0f;
        if (part == 0) bias = sflag ? bs[j] : bf[j];

        floatx4 acc = {bias, bias, bias, bias};
        acc = __builtin_amdgcn_mfma_f32_16x16x32_bf16(a0.s, b0.s, acc, 0, 0, 0);
        acc = __builtin_amdgcn_mfma_f32_16x16x32_bf16(a1.s, b1.s, acc, 0, 0, 0);

#pragma unroll
        for (int r = 0; r < 4; ++r)
            L[(quad * 4 + r) * NSTR + col] = bf16_1(acc[r]);
    }

    // wave-private tile -> coalesced stores (no barrier needed; same wave)
#pragma unroll
    for (int it = 0; it < 4; ++it) {
        const int node_l = it * 4 + quad;            // local node 0..15
        const int c8     = n16 * 8;                  // col group (8 ushorts)
        uint4 v = *(const uint4*)(L + node_l * NSTR + c8);
        *(uint4*)(Tout + (size_t)(ntile * 16 + node_l) * 128 + c8) = v;
    }
}

// ---- edge kernel with fused segmented aggregation -------------------------
__global__ __launch_bounds__(256) void edge_message_mfma(
    const unsigned short* __restrict__ Tdst,  // [N_NODES][128] bf16
    const unsigned short* __restrict__ Tsrc,  // [N_NODES][128] bf16
    const unsigned short* __restrict__ eaS,   // [N_EDGES][32] bf16, sorted
    const int2* __restrict__ sd_sorted,       // [N_EDGES] (src,dst) sorted
    const float* __restrict__ Wf,             // rows 128..159 used
    const float* __restrict__ Ws,
    float* __restrict__ hout)                 // [N_NODES][64], pre-init = hin
{
    __shared__ float lds[4][16 * LSTR];
    const int lane = threadIdx.x & 63;
    const int wid  = threadIdx.x >> 6;
    const int n16  = lane & 15;
    const int quad = lane >> 4;
    const int c0   = quad * 8;
    float* L = lds[wid];

    Frag bfr[4], bsr[4];
#pragma unroll
    for (int jb = 0; jb < 4; ++jb) {
        const int j = jb * 16 + n16;
        float tf[8], tsv[8];
#pragma unroll
        for (int i = 0; i < 8; ++i) {
            tf[i]  = Wf[(128 + c0 + i) * 64 + j];
            tsv[i] = Ws[(128 + c0 + i) * 64 + j];
        }
#pragma unroll
        for (int p = 0; p < 4; ++p) {
            bfr[jb].u[p] = pk_bf16(tf[2 * p], tf[2 * p + 1]);
            bsr[jb].u[p] = pk_bf16(tsv[2 * p], tsv[2 * p + 1]);
        }
    }

    const floatx4 zero = {0.0f, 0.0f, 0.0f, 0.0f};
    const int nwaves = gridDim.x * 4;
    for (int t = blockIdx.x * 4 + wid; t < NTILE; t += nwaves) {
        const int p0 = t * 16;

        // per-tile metadata: lanes 0..15 meaningful (others mirror)
        const int2 sd = sd_sorted[p0 + n16];
        const int sv16 = sd.x;
        const int dv16 = sd.y;

        // A fragment: one coalesced 16B bf16 load (sorted layout)
        Frag af;
        af.s = *(const short8*)(eaS + (size_t)(p0 + n16) * 32 + c0);

        floatx4 accf[4], accs[4];
#pragma unroll
        for (int jb = 0; jb < 4; ++jb) {
            accf[jb] = __builtin_amdgcn_mfma_f32_16x16x32_bf16(af.s, bfr[jb].s, zero, 0, 0, 0);
            accs[jb] = __builtin_amdgcn_mfma_f32_16x16x32_bf16(af.s, bsr[jb].s, zero, 0, 0, 0);
        }

        // activation + write message rows into wave-private LDS
#pragma unroll
        for (int r = 0; r < 4; ++r) {
            const int m = quad * 4 + r;               // row (sorted pos p0+m)
            const int sv = __shfl(sv16, m);           // src of row m
            const int dv = __shfl(dv16, m);           // dst of row m
            const unsigned short* td = Tdst + (size_t)dv * 128;
            const unsigned short* ts = Tsrc + (size_t)sv * 128;
#pragma unroll
            for (int jb = 0; jb < 4; ++jb) {
                const int j = jb * 16 + n16;
                unsigned d2 = *(const unsigned*)(td + 2 * j);
                unsigned s2 = *(const unsigned*)(ts + 2 * j);
                float vf = accf[jb][r] + upk(d2 & 0xFFFFu) + upk(s2 & 0xFFFFu);
                float vs = accs[jb][r] + upk(d2 >> 16) + upk(s2 >> 16);
                float sig = __builtin_amdgcn_rcpf(1.0f + __expf(-vf));
                float spl = fmaxf(vs, 0.0f) + __logf(1.0f + __expf(-fabsf(vs)));
                L[m * LSTR + j] = sig * spl;
            }
        }

        // segmented scan over the 16 rows (dst runs), lane = channel
        {
            int cur = __builtin_amdgcn_readlane(dv16, 0);
            float acc = L[0 * LSTR + lane];
#pragma unroll
            for (int r = 1; r < 16; ++r) {
                int d = __builtin_amdgcn_readlane(dv16, r);
                float v = L[r * LSTR + lane];
                if (d != cur) {
                    atomicAdd(&hout[(size_t)cur * D + lane], acc);
                    cur = d; acc = v;
                } else {
                    acc += v;
                }
            }
            atomicAdd(&hout[(size_t)cur * D + lane], acc);
        }
    }
}

// segment_sum(h, batch) into pooled[N_GRAPHS][64]
__global__ __launch_bounds__(256) void pool_kernel(
    const float* __restrict__ h,
    const int* __restrict__ batch,
    float* __restrict__ pooled)
{
    const int lane = threadIdx.x & 63;
    const int wid  = threadIdx.x >> 6;
    const int n = blockIdx.x * 4 + wid;
    if (n >= N_NODES) return;
    atomicAdd(&pooled[(size_t)batch[n] * D + lane], h[(size_t)n * D + lane]);
}

__global__ __launch_bounds__(256) void out_kernel(
    const float* __restrict__ pooled,
    const float* __restrict__ Wout,
    const float* __restrict__ bout,
    float* __restrict__ out)
{
    const int g = blockIdx.x * blockDim.x + threadIdx.x;
    if (g >= N_GRAPHS) return;
    float acc = bout[0];
#pragma unroll
    for (int j = 0; j < D; ++j) acc = fmaf(pooled[(size_t)g * D + j], Wout[j], acc);
    out[g] = acc;
}

extern "C" void kernel_launch(void* const* d_in, const int* in_sizes, int n_in,
                              void* d_out, int out_size, void* d_ws, size_t ws_size,
                              hipStream_t stream) {
    const float* x     = (const float*)d_in[0];
    const int*   ei    = (const int*)  d_in[1];
    const float* ea    = (const float*)d_in[2];
    const int*   batch = (const int*)  d_in[3];
    const float* Wf1   = (const float*)d_in[4];
    const float* bf1   = (const float*)d_in[5];
    const float* Ws1   = (const float*)d_in[6];
    const float* bs1   = (const float*)d_in[7];
    const float* Wf2   = (const float*)d_in[8];
    const float* bf2   = (const float*)d_in[9];
    const float* Ws2   = (const float*)d_in[10];
    const float* bs2   = (const float*)d_in[11];
    const float* Wout  = (const float*)d_in[12];
    const float* bout  = (const float*)d_in[13];
    float* out = (float*)d_out;

    // workspace carve (~110 MB)
    char* base = (char*)d_ws;
    size_t o = 0;
    unsigned short* Tdst = (unsigned short*)(base + o); o += (size_t)N_NODES * 128 * 2;
    unsigned short* Tsrc = (unsigned short*)(base + o); o += (size_t)N_NODES * 128 * 2;
    unsigned short* eaS  = (unsigned short*)(base + o); o += (size_t)N_EDGES * 32 * 2;
    float* h1     = (float*)(base + o); o += (size_t)N_NODES * D * 4;
    float* h2     = (float*)(base + o); o += (size_t)N_NODES * D * 4;
    float* pooled = (float*)(base + o); o += (size_t)N_GRAPHS * D * 4;
    int* deg  = (int*)(base + o); o += (size_t)N_NODES * 4;
    int* off  = (int*)(base + o); o += (size_t)(N_NODES + 1) * 4;
    int* tsum = (int*)(base + o); o += 256 * 4;
    int2* sd_sorted = (int2*)(base + o); o += (size_t)N_EDGES * 8;

    // ---- CSR build + fused ea pack ----
    hipMemsetAsync(deg, 0, (size_t)N_NODES * 4, stream);
    hist_kernel<<<N_EDGES / 256, 256, 0, stream>>>(ei, deg);
    scan1<<<NB_SCAN, 256, 0, stream>>>(deg, off, tsum);
    scan2<<<1, 256, 0, stream>>>(tsum);
    scan3<<<NB_SCAN, 256, 0, stream>>>(off, tsum);
    hipMemsetAsync(deg, 0, (size_t)N_NODES * 4, stream);
    scatter_pack<<<N_EDGES / 256, 256, 0, stream>>>(ei, off, deg, ea, eaS, sd_sorted);

    // ---- layer 1 ----
    node_transform_mfma<<<1563, 256, 0, stream>>>(x, Wf1, Ws1, bf1, bs1, Tdst, Tsrc);
    hipMemcpyAsync(h1, x, (size_t)N_NODES * D * 4, hipMemcpyDeviceToDevice, stream);
    edge_message_mfma<<<3125, 256, 0, stream>>>(Tdst, Tsrc, eaS,
                                                sd_sorted, Wf1, Ws1, h1);

    // ---- layer 2 ----
    node_transform_mfma<<<1563, 256, 0, stream>>>(h1, Wf2, Ws2, bf2, bs2, Tdst, Tsrc);
    hipMemcpyAsync(h2, h1, (size_t)N_NODES * D * 4, hipMemcpyDeviceToDevice, stream);
    edge_message_mfma<<<3125, 256, 0, stream>>>(Tdst, Tsrc, eaS,
                                                sd_sorted, Wf2, Ws2, h2);

    // ---- pool + out ----
    hipMemsetAsync(pooled, 0, (size_t)N_GRAPHS * D * 4, stream);
    pool_kernel<<<12500, 256, 0, stream>>>(h2, batch, pooled);
    out_kernel<<<2, 256, 0, stream>>>(pooled, Wout, bout, out);
}